// Round 21
// baseline (18.414 us; speedup 1.0000x reference)
//
#include <hip/hip_runtime.h>

// Problem constants
constexpr int B_   = 2;
constexpr int CIN  = 64;
constexpr int N    = 128;
constexpr int T    = 24;
constexpr int HID  = 64;
constexpr int COUT = 64;
constexpr int NT   = N * T;             // 3072
constexpr int BT   = B_ * T;            // 48
constexpr int ATT_BLOCKS = B_ * N;      // 256
constexpr int XT_BLOCKS  = 32;
constexpr int WF_BLOCKS  = 16;
constexpr int PREP_BLOCKS = ATT_BLOCKS + XT_BLOCKS + WF_BLOCKS;  // 304
constexpr int MAIN_BLOCKS = BT * 2;     // 96 = (bt, i-half)

typedef __attribute__((ext_vector_type(8))) short short8;
typedef __attribute__((ext_vector_type(4))) float f32x4;

__device__ inline unsigned short f2bf(float f) {   // RNE float->bf16
    unsigned u = __float_as_uint(f);
    return (unsigned short)((u + 0x7FFFu + ((u >> 16) & 1u)) >> 16);
}

// ---------------------------------------------------------------------------
// k_prep: R13 structure; input loads NON-TEMPORAL (loads are safe: input
// lines are never dirty in any L2 at replay time — written once by host,
// only read thereafter). NT *stores* were the R20 correctness hazard
// (harness poison leaves dirty 0xAA lines that NT stores don't invalidate)
// and are NOT used anywhere in this round.
// ---------------------------------------------------------------------------
__global__ __launch_bounds__(256) void k_prep(
    const float* __restrict__ x,
    const float* __restrict__ att,
    const float* __restrict__ W1,
    const float* __restrict__ b1,
    const float* __restrict__ W2,
    const float* __restrict__ b2,
    unsigned* __restrict__ xT32,
    unsigned* __restrict__ attT32,
    float* __restrict__ asum_g,
    unsigned short* __restrict__ WfvT,
    unsigned short* __restrict__ WfhT,
    float* __restrict__ bvb2,
    float* __restrict__ bh)
{
    __shared__ __align__(16) unsigned smem_u32[8320];
    const int tid = threadIdx.x;
    const int blk = blockIdx.x;

    if (blk < ATT_BLOCKS) {
        float* ts   = (float*)smem_u32;          // [128][25]
        float* psum = ts + 3200;                 // [24][8]
        const int b = blk >> 7;
        const int i = blk & 127;

        const float* ab = att + ((size_t)b * N + i) * NT;
#pragma unroll
        for (int u = 0; u < 12; ++u) {
            const int idx = tid + 256 * u;
            const int j = idx / T, t = idx - j * T;
            ts[j * 25 + t] = __builtin_nontemporal_load(&ab[idx]);  // NT load: read-once
        }
        __syncthreads();
#pragma unroll
        for (int u = 0; u < 6; ++u) {
            const int e2 = tid + 256 * u;
            const int t = e2 >> 6, jp = e2 & 63, j = jp * 2;
            const unsigned pk = (unsigned)f2bf(ts[j * 25 + t])
                              | ((unsigned)f2bf(ts[(j + 1) * 25 + t]) << 16);
            attT32[((size_t)(b * T + t) * N + i) * 64 + jp] = pk;
        }
        if (tid < 192) {
            const int t = tid >> 3, p = tid & 7;
            float s = 0.f;
#pragma unroll
            for (int q = 0; q < 16; ++q) s += ts[(p * 16 + q) * 25 + t];
            psum[t * 8 + p] = s;
        }
        __syncthreads();
        if (tid < T) {
            float s = 0.f;
#pragma unroll
            for (int p = 0; p < 8; ++p) s += psum[tid * 8 + p];
            asum_g[(size_t)(b * T + tid) * N + i] = s;
        }
    } else if (blk < ATT_BLOCKS + XT_BLOCKS) {
        const int tb = blk - ATT_BLOCKS;
        const int b  = tb >> 4;
        const int n0 = (tb & 15) * 8;
#pragma unroll
        for (int u = 0; u < 12; ++u) {
            const int vidx = tid + 256 * u;
            const int cp = vidx / 48, w48 = vidx - cp * 48;
            const f32x4* vp = (const f32x4*)(x + (size_t)(b * CIN + cp) * NT
                                             + n0 * T + w48 * 4);
            const f32x4 v = __builtin_nontemporal_load(vp);         // NT load: read-once
            smem_u32[cp * 97 + w48 * 2]     = (unsigned)f2bf(v[0]) | ((unsigned)f2bf(v[1]) << 16);
            smem_u32[cp * 97 + w48 * 2 + 1] = (unsigned)f2bf(v[2]) | ((unsigned)f2bf(v[3]) << 16);
        }
        __syncthreads();
#pragma unroll
        for (int v = 0; v < 24; ++v) {
            const int oidx = tid + 256 * v;
            const int t = oidx >> 8, rem = oidx & 255;
            const int n = rem >> 5, cp = rem & 31;
            const int r = n * T + t;
            const unsigned w0 = smem_u32[(2 * cp) * 97 + (r >> 1)];
            const unsigned w1 = smem_u32[(2 * cp + 1) * 97 + (r >> 1)];
            const unsigned v0 = (r & 1) ? (w0 >> 16) : (w0 & 0xFFFFu);
            const unsigned v1 = (r & 1) ? (w1 >> 16) : (w1 & 0xFFFFu);
            xT32[((size_t)(b * T + t) * N + n0 + n) * 32 + cp] = v0 | (v1 << 16);
        }
    } else {
        const int wf   = blk - (ATT_BLOCKS + XT_BLOCKS);
        const int half = wf >> 3;
        const int c0   = (wf & 7) * 8;
        float* sW1 = (float*)smem_u32;          // [64][65]
        float* sW2 = sW1 + 64 * 65;             // [64][65]
#pragma unroll
        for (int u = 0; u < 16; ++u) {
            const int i = tid + 256 * u;
            const int r = i >> 6, q = i & 63;
            sW1[r * 65 + q] = W1[i];
            sW2[r * 65 + q] = W2[half * 4096 + i];
        }
        __syncthreads();

        const int c = c0 + (tid & 7);
        const int r = tid >> 3;
        float a0 = 0.f, a1 = 0.f;
#pragma unroll
        for (int q = 0; q < 64; ++q) {
            const float w2 = sW2[q * 65 + c];
            a0 += sW1[r * 65 + q] * w2;
            a1 += sW1[(r + 32) * 65 + q] * w2;
        }
        unsigned short* dst = half ? WfhT : WfvT;
        dst[c * 64 + r]      = f2bf(a0);
        dst[c * 64 + r + 32] = f2bf(a1);

        if (tid < 8) {
            const int cb = c0 + tid;
            float s = 0.f;
#pragma unroll
            for (int q = 0; q < 64; ++q) s += b1[q] * sW2[q * 65 + cb];
            if (half) bh[cb] = s;
            else      bvb2[cb] = s + b2[cb];
        }
    }
}

// ---------------------------------------------------------------------------
// k_main: R19-identical (normal stores everywhere — NT stores reverted).
// ---------------------------------------------------------------------------
__global__ __launch_bounds__(512) void k_main(
    const unsigned* __restrict__ xT32,
    const unsigned* __restrict__ attT32,
    const unsigned short* __restrict__ WfvT,
    const unsigned short* __restrict__ WfhT,
    const float* __restrict__ bvb2,
    const float* __restrict__ bh,
    const float* __restrict__ asum_g,
    float* __restrict__ out)
{
    __shared__ __align__(16) unsigned x_lds[128][36];        // 18,432 B
    __shared__ __align__(16) unsigned att_lds[64][68];       // 17,408 B
    __shared__ __align__(16) unsigned short mh_lds[64][136]; // 17,408 B

    const int blk   = blockIdx.x;
    const int ihalf = blk & 1;
    const int bt    = blk >> 1;
    const int b     = bt / T;
    const int t     = bt - b * T;

    const int tid  = threadIdx.x;
    const int w    = tid >> 6;
    const int lane = tid & 63;
    const int c16  = lane & 15;
    const int q4   = lane >> 4;

    // ---- Stage 0: linear streams of ws (L2-warm; keep cached) ----
    {
        const uint4* src = (const uint4*)(xT32 + (size_t)bt * 4096);
#pragma unroll
        for (int u = 0; u < 2; ++u) {
            const int vi = tid + 512 * u;
            const uint4 v = src[vi];
            *(uint4*)&x_lds[vi >> 3][(vi & 7) * 4] = v;
        }
    }
    {
        const uint4* src = (const uint4*)(attT32 + ((size_t)bt * 128 + ihalf * 64) * 64);
#pragma unroll
        for (int u = 0; u < 2; ++u) {
            const int vi = tid + 512 * u;
            const uint4 v = src[vi];
            *(uint4*)&att_lds[vi >> 4][(vi & 15) * 4] = v;
        }
    }

    // ---- Small global loads (weights/biases/asum — tiny, broadcast) ----
    const int ct0 = (w >> 2) * 2;
    short8 wh0[4], wh1[4];
#pragma unroll
    for (int ct = 0; ct < 4; ++ct) {
        wh0[ct] = *(const short8*)(WfhT + (ct * 16 + c16) * 64 + q4 * 8);
        wh1[ct] = *(const short8*)(WfhT + (ct * 16 + c16) * 64 + 32 + q4 * 8);
    }
    short8 wv0[2], wv1[2];
#pragma unroll
    for (int p = 0; p < 2; ++p) {
        wv0[p] = *(const short8*)(WfvT + ((ct0 + p) * 16 + c16) * 64 + q4 * 8);
        wv1[p] = *(const short8*)(WfvT + ((ct0 + p) * 16 + c16) * 64 + 32 + q4 * 8);
    }
    float bhc[4];
#pragma unroll
    for (int ct = 0; ct < 4; ++ct) bhc[ct] = bh[ct * 16 + c16];
    float bvc[2];
#pragma unroll
    for (int p = 0; p < 2; ++p) bvc[p] = bvb2[(ct0 + p) * 16 + c16];

    const int il_base = ihalf * 64 + (w & 3) * 16;
    const f32x4 as4 = *(const f32x4*)(asum_g + (size_t)bt * N + il_base + q4 * 4);

    __syncthreads();

    // ---- Phase 1: mh (n-tile w, all c) -> LDS ; mv (own phase-2 tile) -> regs
    const short8 a0 = *(const short8*)&x_lds[w * 16 + c16][q4 * 4];
    const short8 a1 = *(const short8*)&x_lds[w * 16 + c16][16 + q4 * 4];
    const int nt_mv = ihalf * 4 + (w & 3);
    const short8 m0 = *(const short8*)&x_lds[nt_mv * 16 + c16][q4 * 4];
    const short8 m1 = *(const short8*)&x_lds[nt_mv * 16 + c16][16 + q4 * 4];

#pragma unroll
    for (int ct = 0; ct < 4; ++ct) {
        f32x4 d = {0.f, 0.f, 0.f, 0.f};
        d = __builtin_amdgcn_mfma_f32_16x16x32_bf16(a0, wh0[ct], d, 0, 0, 0);
        d = __builtin_amdgcn_mfma_f32_16x16x32_bf16(a1, wh1[ct], d, 0, 0, 0);
        uint2 pk;
        pk.x = (unsigned)f2bf(d[0] + bhc[ct]) | ((unsigned)f2bf(d[1] + bhc[ct]) << 16);
        pk.y = (unsigned)f2bf(d[2] + bhc[ct]) | ((unsigned)f2bf(d[3] + bhc[ct]) << 16);
        *(uint2*)&mh_lds[ct * 16 + c16][w * 16 + q4 * 4] = pk;
    }
    f32x4 dv0 = {0.f, 0.f, 0.f, 0.f}, dv1 = {0.f, 0.f, 0.f, 0.f};
    dv0 = __builtin_amdgcn_mfma_f32_16x16x32_bf16(m0, wv0[0], dv0, 0, 0, 0);
    dv0 = __builtin_amdgcn_mfma_f32_16x16x32_bf16(m1, wv1[0], dv0, 0, 0, 0);
    dv1 = __builtin_amdgcn_mfma_f32_16x16x32_bf16(m0, wv0[1], dv1, 0, 0, 0);
    dv1 = __builtin_amdgcn_mfma_f32_16x16x32_bf16(m1, wv1[1], dv1, 0, 0, 0);

    __syncthreads();

    // ---- Phase 2: einsum for i-tile (w&3) of this half, c-pair ct0 ----
    f32x4 acc0 = {0.f, 0.f, 0.f, 0.f}, acc1 = {0.f, 0.f, 0.f, 0.f};
    const int ir = (w & 3) * 16 + c16;
#pragma unroll
    for (int ks = 0; ks < 4; ++ks) {
        const short8 a  = *(const short8*)&att_lds[ir][ks * 16 + q4 * 4];
        const short8 b0 = *(const short8*)&mh_lds[ct0 * 16 + c16][ks * 32 + q4 * 8];
        const short8 b1 = *(const short8*)&mh_lds[(ct0 + 1) * 16 + c16][ks * 32 + q4 * 8];
        acc0 = __builtin_amdgcn_mfma_f32_16x16x32_bf16(a, b0, acc0, 0, 0, 0);
        acc1 = __builtin_amdgcn_mfma_f32_16x16x32_bf16(a, b1, acc1, 0, 0, 0);
    }

    // ---- Epilogue: plain stores (R19 pattern) ----
    {
        const int cc0 = ct0 * 16 + c16;
        const int cc1 = (ct0 + 1) * 16 + c16;
        float* ob0 = out + (((size_t)b * COUT + cc0) * N + il_base + q4 * 4) * T + t;
        float* ob1 = out + (((size_t)b * COUT + cc1) * N + il_base + q4 * 4) * T + t;
#pragma unroll
        for (int e = 0; e < 4; ++e) {
            ob0[e * T] = acc0[e] + as4[e] * (dv0[e] + bvc[0]);
            ob1[e * T] = acc1[e] + as4[e] * (dv1[e] + bvc[1]);
        }
    }
}

// ---------------------------------------------------------------------------
extern "C" void kernel_launch(void* const* d_in, const int* in_sizes, int n_in,
                              void* d_out, int out_size, void* d_ws, size_t ws_size,
                              hipStream_t stream)
{
    const float* x   = (const float*)d_in[0];
    const float* att = (const float*)d_in[1];
    const float* W1  = (const float*)d_in[2];
    const float* b1  = (const float*)d_in[3];
    const float* W2  = (const float*)d_in[4];
    const float* b2  = (const float*)d_in[5];
    float* out = (float*)d_out;

    char* ws = (char*)d_ws;
    unsigned*       xT32   = (unsigned*)ws;                        //   786,432 B
    unsigned*       attT32 = (unsigned*)(ws + 786432);             // 1,572,864 B
    float*          asum_g = (float*)(ws + 2359296);               //    24,576 B
    unsigned short* WfvT   = (unsigned short*)(ws + 2383872);      //     8,192 B
    unsigned short* WfhT   = (unsigned short*)(ws + 2392064);      //     8,192 B
    float*          bvb2   = (float*)(ws + 2400256);               //       256 B
    float*          bh     = (float*)(ws + 2400512);               //       256 B

    k_prep<<<PREP_BLOCKS, 256, 0, stream>>>(x, att, W1, b1, W2, b2,
                                            xT32, attT32, asum_g,
                                            WfvT, WfhT, bvb2, bh);
    k_main<<<MAIN_BLOCKS, 512, 0, stream>>>(xT32, attT32,
                                            WfvT, WfhT, bvb2, bh, asum_g, out);
}